// Round 10
// baseline (108.607 us; speedup 1.0000x reference)
//
#include <hip/hip_runtime.h>
#include <hip/hip_bf16.h>
#include <stdint.h>

#define BATCH 16384
#define INF   1024
#define OUTF  2048

#define BM 128
#define BN 128
#define BK 64
#define NT (INF / BK)   // 16 K-tiles

using bf16x8 = __attribute__((ext_vector_type(8))) __bf16;
using f32x4  = __attribute__((ext_vector_type(4))) float;
typedef unsigned short u16;

// round-to-nearest-even f32 -> bf16 (bit pattern)
__device__ __forceinline__ u16 f2bf(float f) {
  unsigned u = __builtin_bit_cast(unsigned, f);
  u += 0x7fffu + ((u >> 16) & 1u);
  return (u16)(u >> 16);
}

__device__ __forceinline__ void load_lds16(const void* g, void* l) {
  __builtin_amdgcn_global_load_lds(
      (const __attribute__((address_space(1))) unsigned*)g,
      (__attribute__((address_space(3))) unsigned*)l, 16, 0, 0);
}

// ---- x: fp32 [BATCH][INF] -> bf16 [BATCH][INF] + row sum-of-squares (fp32) ----
__global__ void __launch_bounds__(256) k_convert_x(const float* __restrict__ x,
                                                   u16* __restrict__ xb,
                                                   float* __restrict__ xsq) {
  const int row = blockIdx.x;
  const int t = threadIdx.x;
  const float4 v = reinterpret_cast<const float4*>(x + (size_t)row * INF)[t];
  ushort4 b4;
  b4.x = f2bf(v.x); b4.y = f2bf(v.y); b4.z = f2bf(v.z); b4.w = f2bf(v.w);
  reinterpret_cast<ushort4*>(xb + (size_t)row * INF)[t] = b4;

  float s = v.x * v.x + v.y * v.y + v.z * v.z + v.w * v.w;
  #pragma unroll
  for (int off = 32; off > 0; off >>= 1) s += __shfl_xor(s, off, 64);
  __shared__ float red[4];
  if ((t & 63) == 0) red[t >> 6] = s;
  __syncthreads();
  if (t == 0) xsq[row] = red[0] + red[1] + red[2] + red[3];
}

// ---- w: fp32 [INF][OUTF] -> FRAGMENT-MAJOR bf16 B + fused per-column sq-partials ----
// Bf element index: (((bx*16 + t)*4 + wc)*8 + f)*512 + l*8 + j   (f = nn*2+ks)
// holds B^T[col][k] with col = bx*256+wc*64+nn*16+(l&15), k = t*64+ks*32+(l>>4)*8+j.
__global__ void __launch_bounds__(256) k_convert_w(const float* __restrict__ w,
                                                   u16* __restrict__ Bf,
                                                   float* __restrict__ part) {
  __shared__ float tile[64][65];   // [k][n]
  __shared__ float psum[4][64];
  const int n0 = blockIdx.x * 64;   // along OUTF
  const int k0 = blockIdx.y * 64;   // along INF
  const int tid = threadIdx.x;
  const int c = tid & 63, r4 = tid >> 6;
  float s = 0.f;
  #pragma unroll
  for (int i = 0; i < 16; ++i) {
    int k = r4 + i * 4;
    float v = w[(size_t)(k0 + k) * OUTF + n0 + c];   // coalesced over n
    tile[k][c] = v;
    s += v * v;
  }
  psum[r4][c] = s;
  __syncthreads();

  const int bx = blockIdx.x >> 2;          // 256-col block
  const int wc = blockIdx.x & 3;           // 64-col sub-block
  const int tt = blockIdx.y;               // K-tile
  u16* base = Bf + ((((size_t)bx * 16 + tt) * 4 + wc) * 8) * 512;
  const int l = tid & 63;
  #pragma unroll
  for (int fh = 0; fh < 2; ++fh) {
    const int f = (tid >> 6) * 2 + fh;     // 0..7
    const int nn = f >> 1, ks = f & 1;
    const int cl = nn * 16 + (l & 15);
    const int kl = ks * 32 + (l >> 4) * 8;
    u16 tmp[8];
    #pragma unroll
    for (int j = 0; j < 8; ++j) tmp[j] = f2bf(tile[kl + j][cl]);
    uint4 v;
    v.x = (unsigned)tmp[0] | ((unsigned)tmp[1] << 16);
    v.y = (unsigned)tmp[2] | ((unsigned)tmp[3] << 16);
    v.z = (unsigned)tmp[4] | ((unsigned)tmp[5] << 16);
    v.w = (unsigned)tmp[6] | ((unsigned)tmp[7] << 16);
    *reinterpret_cast<uint4*>(base + (size_t)f * 512 + (size_t)l * 8) = v;
  }
  if (r4 == 0)
    part[(size_t)blockIdx.y * OUTF + n0 + c] =
        psum[0][c] + psum[1][c] + psum[2][c] + psum[3][c];
}

__global__ void __launch_bounds__(256) k_wsq_final(const float* __restrict__ part,
                                                   float* __restrict__ wsq) {
  const int col = blockIdx.x * 256 + threadIdx.x;
  float s = 0.f;
  #pragma unroll
  for (int kb = 0; kb < 16; ++kb) s += part[(size_t)kb * OUTF + col];
  wsq[col] = s;
}

// ---- fused GEMM: out = xsq[row] + wsq[col] - 2 * (x @ w) ----
// R9 multi-block structure + B removed from LDS (R8 ablation: skeleton = MFMA
// peak; R9 audit: LDS pipe 96 KB/block-tile was the binder). 128x128 tile,
// 4 waves (2x2 of 64x64), BK=64. A: 32 KiB LDS DOUBLE-buffer, T2 swizzle,
// gload_lds, one barrier/tile with exact vmcnt: head vmcnt(0)=A(t) landed ->
// barrier -> issue A(t+1) -> load B(t)->regs (fragment-major, L2-hot panel) ->
// vmcnt(4)=B done, A(t+1) in flight -> 8 ds_read + 64 MFMA. LDS traffic/tile
// halves to 48 KB (< MFMA floor). ~3 blocks/CU cover B's L2 latency.
__global__ void __launch_bounds__(256, 3) k_gemm(const u16* __restrict__ A,
                                                 const u16* __restrict__ Bf,
                                                 const float* __restrict__ xsq,
                                                 const float* __restrict__ wsq,
                                                 float* __restrict__ out) {
  __shared__ __attribute__((aligned(16))) char lds[32768]; // A dbuf 2 x 16 KB

  const int tid = threadIdx.x;
  const int wave = tid >> 6, lane = tid & 63;
  const int bid = blockIdx.x;
  const int xcd = bid & 7;
  const int idx = bid >> 3;                // 0..255
  const int bxn = xcd * 2 + (idx & 1);     // 0..15  (N block, XCD-pinned pair)
  const int by  = idx >> 1;                // 0..127 (M block)
  const int rowBase = by * BM;
  const int colBase = bxn * BN;
  const int wr = (wave >> 1) & 1, wc = wave & 1;   // 2x2 waves of 64x64

  // A staging (linear LDS dest = parity*16K + tid*16 + i*4096; pre-swz source)
  const int srow = tid >> 3;                                          // 0..31
  const int ke   = (((tid & 7) * 16) ^ (((tid >> 3) & 7) << 4)) >> 1; // elem col
  const u16* aS = A + (size_t)(rowBase + srow) * INF + ke;
  char* ldsw = lds + tid * 16;

  auto STAGE_A = [&](int parity, int t) {
    const int kk = t * BK;
    char* dst = ldsw + parity * 16384;
    #pragma unroll
    for (int i = 0; i < 4; ++i)              // rows [i*32, i*32+32)
      load_lds16(aS + (size_t)(i * 32) * INF + kk, dst + i * 4096);
  };

  // A fragment read addressing (swizzled); rows are 128 B
  const int rf  = lane & 15;
  const int hi  = lane >> 4;                 // 0..3
  const int swz = (rf & 7) << 4;
  const int aRd = (wr * 64 + rf) * 128;      // + mm*2048 + ko

  // fragment-major B base: old-layout coords obx = bxn>>1, owc = (bxn&1)*2+wc
  const u16* bBase = Bf
      + ((((size_t)(bxn >> 1) * 16 + 0) * 4 + ((bxn & 1) * 2 + wc)) * 8) * 512
      + (size_t)lane * 8;                    // tile t at +t*16384, frag f at +f*512

  f32x4 acc[4][4] = {};

  STAGE_A(0, 0);                             // prologue: A(0) in flight

  for (int t = 0; t < NT; ++t) {
    asm volatile("s_waitcnt vmcnt(0)" ::: "memory");   // A(t) landed (only A outstanding)
    __builtin_amdgcn_s_barrier();            // all waves' A(t) DMA visible; prev reads done

    if (t + 1 < NT) STAGE_A((t + 1) & 1, t + 1);       // 4 issues into other buffer

    bf16x8 bc[8];
    {
      const u16* bT = bBase + (size_t)t * 16384;
      #pragma unroll
      for (int f = 0; f < 8; ++f)
        bc[f] = *reinterpret_cast<const bf16x8*>(bT + f * 512);
    }
    if (t + 1 < NT) asm volatile("s_waitcnt vmcnt(4)" ::: "memory"); // B(t) done
    else            asm volatile("s_waitcnt vmcnt(0)" ::: "memory");

    const char* buf = lds + (t & 1) * 16384;
    #pragma unroll
    for (int ks = 0; ks < 2; ++ks) {
      const int ko = (ks * 64 + hi * 16) ^ swz;
      bf16x8 a[4];
      #pragma unroll
      for (int mm = 0; mm < 4; ++mm)
        a[mm] = *reinterpret_cast<const bf16x8*>(buf + aRd + mm * 2048 + ko);
      __builtin_amdgcn_s_setprio(1);
      #pragma unroll
      for (int mm = 0; mm < 4; ++mm)
        #pragma unroll
        for (int nn = 0; nn < 4; ++nn)
          acc[mm][nn] = __builtin_amdgcn_mfma_f32_16x16x32_bf16(
              a[mm], bc[nn * 2 + ks], acc[mm][nn], 0, 0, 0);
      __builtin_amdgcn_s_setprio(0);
    }
  }

  // ---- epilogue: C/D layout col = lane&15, row = (lane>>4)*4 + j ----
  const int cj = lane & 15;
  const int rg = hi * 4;
  #pragma unroll
  for (int m = 0; m < 4; ++m) {
    #pragma unroll
    for (int j = 0; j < 4; ++j) {
      const int row = rowBase + wr * 64 + m * 16 + rg + j;
      const float xs = xsq[row];
      #pragma unroll
      for (int n = 0; n < 4; ++n) {
        const int col = colBase + wc * 64 + n * 16 + cj;
        out[(size_t)row * OUTF + col] = xs + wsq[col] - 2.0f * acc[m][n][j];
      }
    }
  }
}

extern "C" void kernel_launch(void* const* d_in, const int* in_sizes, int n_in,
                              void* d_out, int out_size, void* d_ws, size_t ws_size,
                              hipStream_t stream) {
  const float* x = (const float*)d_in[0];
  const float* w = (const float*)d_in[1];
  float* out = (float*)d_out;

  char* ws = (char*)d_ws;
  u16* xb    = (u16*)(ws);                    // 16384*1024*2 = 33554432 B
  u16* Bf    = (u16*)(ws + 33554432);         // 2048*1024*2  =  4194304 B (fragment-major)
  float* xsq = (float*)(ws + 37748736);       // 16384*4      =    65536 B
  float* wsq = (float*)(ws + 37814272);       // 2048*4       =     8192 B
  float* prt = (float*)(ws + 37822464);       // 16*2048*4    =   131072 B

  k_convert_x<<<BATCH, 256, 0, stream>>>(x, xb, xsq);
  k_convert_w<<<dim3(OUTF / 64, INF / 64), 256, 0, stream>>>(w, Bf, prt);
  k_wsq_final<<<OUTF / 256, 256, 0, stream>>>(prt, wsq);
  k_gemm<<<(BATCH / BM) * (OUTF / BN), 256, 0, stream>>>(xb, Bf, xsq, wsq, out);
}

// Round 11
// 101.122 us; speedup vs baseline: 1.0740x; 1.0740x over previous
//
#include <hip/hip_runtime.h>
#include <hip/hip_bf16.h>
#include <stdint.h>

#define BATCH 16384
#define INF   1024
#define OUTF  2048

#define BM 128
#define BN 128
#define BK 64
#define NT (INF / BK)   // 16 K-tiles

using bf16x8 = __attribute__((ext_vector_type(8))) __bf16;
using f32x4  = __attribute__((ext_vector_type(4))) float;
typedef unsigned short u16;

// round-to-nearest-even f32 -> bf16 (bit pattern)
__device__ __forceinline__ u16 f2bf(float f) {
  unsigned u = __builtin_bit_cast(unsigned, f);
  u += 0x7fffu + ((u >> 16) & 1u);
  return (u16)(u >> 16);
}

__device__ __forceinline__ void load_lds16(const void* g, void* l) {
  __builtin_amdgcn_global_load_lds(
      (const __attribute__((address_space(1))) unsigned*)g,
      (__attribute__((address_space(3))) unsigned*)l, 16, 0, 0);
}

// ---- x: fp32 [BATCH][INF] -> bf16 + row sum-of-squares. Wave-per-row. ----
__global__ void __launch_bounds__(256) k_convert_x(const float* __restrict__ x,
                                                   u16* __restrict__ xb,
                                                   float* __restrict__ xsq) {
  const int row = blockIdx.x * 4 + (threadIdx.x >> 6);
  const int l = threadIdx.x & 63;
  const float* xr = x + (size_t)row * INF;
  u16* xbr = xb + (size_t)row * INF;
  float s = 0.f;
  #pragma unroll
  for (int i = 0; i < 4; ++i) {
    const float4 v = reinterpret_cast<const float4*>(xr)[l + i * 64];
    ushort4 b4;
    b4.x = f2bf(v.x); b4.y = f2bf(v.y); b4.z = f2bf(v.z); b4.w = f2bf(v.w);
    reinterpret_cast<ushort4*>(xbr)[l + i * 64] = b4;
    s += v.x * v.x + v.y * v.y + v.z * v.z + v.w * v.w;
  }
  #pragma unroll
  for (int off = 32; off > 0; off >>= 1) s += __shfl_xor(s, off, 64);
  if (l == 0) xsq[row] = s;
}

// ---- w: fp32 [INF][OUTF] -> bf16 w^T [OUTF][INF] + fused per-column sq-partials ----
__global__ void __launch_bounds__(256) k_convert_w(const float* __restrict__ w,
                                                   u16* __restrict__ wt,
                                                   float* __restrict__ part) {
  __shared__ float tile[64][65];
  __shared__ float psum[4][64];
  const int n0 = blockIdx.x * 64;   // along OUTF
  const int k0 = blockIdx.y * 64;   // along INF
  const int t = threadIdx.x;
  const int c = t & 63, r4 = t >> 6;
  float s = 0.f;
  #pragma unroll
  for (int i = 0; i < 16; ++i) {
    int k = r4 + i * 4;
    float v = w[(size_t)(k0 + k) * OUTF + n0 + c];   // coalesced over n
    tile[k][c] = v;
    s += v * v;
  }
  psum[r4][c] = s;
  __syncthreads();
  #pragma unroll
  for (int i = 0; i < 16; ++i) {
    int n = r4 + i * 4;
    wt[(size_t)(n0 + n) * INF + k0 + c] = f2bf(tile[c][n]);  // coalesced over k
  }
  if (r4 == 0)
    part[(size_t)blockIdx.y * OUTF + n0 + c] =
        psum[0][c] + psum[1][c] + psum[2][c] + psum[3][c];
}

// ---- fused GEMM: out = xsq[row] + wsq[col] - 2 * (x @ w) ----
// R9 structure verbatim (best measured: 80.3 us, 852 TF = documented plain-HIP
// K=1024 ceiling): 128x128 tile, 4 waves (2x2 of 64x64), BK=64, single-buffered
// 32 KiB static LDS, multi-block residency (VGPR<=128 via __launch_bounds__)
// for cross-block stage/compute overlap. T2 swizzle both-sides. XCD-pinned
// column pairs. NEW: wsq computed in-epilogue from partials (LDS reused after
// K-loop) -> k_wsq_final launch removed.
__global__ void __launch_bounds__(256, 4) k_gemm(const u16* __restrict__ A,
                                                 const u16* __restrict__ Bt,
                                                 const float* __restrict__ xsq,
                                                 const float* __restrict__ prt,
                                                 float* __restrict__ out) {
  __shared__ __attribute__((aligned(16))) char lds[32768]; // A 16K @0, B 16K @16384

  const int tid = threadIdx.x;
  const int wave = tid >> 6, lane = tid & 63;
  const int bid = blockIdx.x;
  const int xcd = bid & 7;
  const int idx = bid >> 3;                // 0..255
  const int bxn = xcd * 2 + (idx & 1);     // 0..15  (N block, XCD-pinned pair)
  const int by  = idx >> 1;                // 0..127 (M block)
  const int rowBase = by * BM;
  const int colBase = bxn * BN;
  const int wr = (wave >> 1) & 1, wc = wave & 1;   // 2x2 waves of 64x64

  // staging (linear LDS dest = tid*16 + i*4096; pre-swizzled global source)
  const int srow = tid >> 3;                                          // 0..31
  const int ke   = (((tid & 7) * 16) ^ (((tid >> 3) & 7) << 4)) >> 1; // elem col
  const u16* aS = A  + (size_t)(rowBase + srow) * INF + ke;
  const u16* bS = Bt + (size_t)(colBase + srow) * INF + ke;
  char* ldsw = lds + tid * 16;

  // fragment read addressing (swizzled); rows are 128 B
  const int rf  = lane & 15;
  const int hi  = lane >> 4;                 // 0..3
  const int swz = (rf & 7) << 4;
  const int aRd = (wr * 64 + rf) * 128;              // + mm*2048 + ko
  const int bRd = 16384 + (wc * 64 + rf) * 128;      // + nn*2048 + ko

  f32x4 acc[4][4] = {};

  for (int t = 0; t < NT; ++t) {
    __builtin_amdgcn_s_barrier();            // everyone done reading prev tile
    const int kk = t * BK;
    #pragma unroll
    for (int i = 0; i < 4; ++i)              // A rows [i*32, i*32+32)
      load_lds16(aS + (size_t)(i * 32) * INF + kk, ldsw + i * 4096);
    #pragma unroll
    for (int i = 0; i < 4; ++i)              // B rows
      load_lds16(bS + (size_t)(i * 32) * INF + kk, ldsw + 16384 + i * 4096);
    asm volatile("s_waitcnt vmcnt(0)" ::: "memory");
    __builtin_amdgcn_s_barrier();            // tile t staged for all waves

    #pragma unroll
    for (int ks = 0; ks < 2; ++ks) {
      const int ko = (ks * 64 + hi * 16) ^ swz;
      bf16x8 b[4];
      #pragma unroll
      for (int nn = 0; nn < 4; ++nn)
        b[nn] = *reinterpret_cast<const bf16x8*>(lds + bRd + nn * 2048 + ko);
      __builtin_amdgcn_s_setprio(1);
      #pragma unroll
      for (int mm = 0; mm < 4; ++mm) {
        bf16x8 a = *reinterpret_cast<const bf16x8*>(lds + aRd + mm * 2048 + ko);
        #pragma unroll
        for (int nn = 0; nn < 4; ++nn)
          acc[mm][nn] = __builtin_amdgcn_mfma_f32_16x16x32_bf16(
              a, b[nn], acc[mm][nn], 0, 0, 0);
      }
      __builtin_amdgcn_s_setprio(0);
    }
  }

  // ---- epilogue: wsq from partials via dead LDS, then fused write ----
  __syncthreads();                            // all waves done with A/B in LDS
  float* wlds = reinterpret_cast<float*>(lds);
  if (tid < BN) {
    float sw = 0.f;
    #pragma unroll
    for (int kb = 0; kb < 16; ++kb)
      sw += prt[(size_t)kb * OUTF + colBase + tid];   // coalesced 512 B per kb
    wlds[tid] = sw;
  }
  __syncthreads();

  const int cj = lane & 15;
  const int rg = hi * 4;
  float wsq_n[4];
  #pragma unroll
  for (int n = 0; n < 4; ++n) wsq_n[n] = wlds[wc * 64 + n * 16 + cj];

  #pragma unroll
  for (int m = 0; m < 4; ++m) {
    #pragma unroll
    for (int j = 0; j < 4; ++j) {
      const int row = rowBase + wr * 64 + m * 16 + rg + j;
      const float xs = xsq[row];
      #pragma unroll
      for (int n = 0; n < 4; ++n) {
        const int col = colBase + wc * 64 + n * 16 + cj;
        out[(size_t)row * OUTF + col] = xs + wsq_n[n] - 2.0f * acc[m][n][j];
      }
    }
  }
}

extern "C" void kernel_launch(void* const* d_in, const int* in_sizes, int n_in,
                              void* d_out, int out_size, void* d_ws, size_t ws_size,
                              hipStream_t stream) {
  const float* x = (const float*)d_in[0];
  const float* w = (const float*)d_in[1];
  float* out = (float*)d_out;

  char* ws = (char*)d_ws;
  u16* xb    = (u16*)(ws);                    // 16384*1024*2 = 33554432 B
  u16* wt    = (u16*)(ws + 33554432);         // 2048*1024*2  =  4194304 B (B^T)
  float* xsq = (float*)(ws + 37748736);       // 16384*4      =    65536 B
  float* prt = (float*)(ws + 37822464);       // 16*2048*4    =   131072 B

  k_convert_x<<<BATCH / 4, 256, 0, stream>>>(x, xb, xsq);
  k_convert_w<<<dim3(OUTF / 64, INF / 64), 256, 0, stream>>>(w, wt, prt);
  k_gemm<<<(BATCH / BM) * (OUTF / BN), 256, 0, stream>>>(xb, wt, xsq, prt, out);
}

// Round 12
// 70.657 us; speedup vs baseline: 1.5371x; 1.4312x over previous
//
#include <hip/hip_runtime.h>
#include <hip/hip_bf16.h>
#include <stdint.h>

#define BATCH 16384
#define INF   1024
#define OUTF  2048

#define BM 128
#define BN 128
#define BK 128
#define NT (INF / BK)   // 8 K-tiles

typedef unsigned char u8;
typedef unsigned int u32;
using i32x4  = __attribute__((ext_vector_type(4))) int;
using i32x8  = __attribute__((ext_vector_type(8))) int;
using f32x16 = __attribute__((ext_vector_type(16))) float;

// pack 4 f32 -> 4 OCP e4m3 bytes via HW cvt (RNE, saturating)
__device__ __forceinline__ u32 pk4_fp8(float a, float b, float c, float d) {
  int v = __builtin_amdgcn_cvt_pk_fp8_f32(a, b, 0, false);    // bytes 0,1
  v = __builtin_amdgcn_cvt_pk_fp8_f32(c, d, v, true);         // bytes 2,3
  return (u32)v;
}

__device__ __forceinline__ void load_lds16(const void* g, void* l) {
  __builtin_amdgcn_global_load_lds(
      (const __attribute__((address_space(1))) unsigned*)g,
      (__attribute__((address_space(3))) unsigned*)l, 16, 0, 0);
}

// ---- x: fp32 [BATCH][INF] -> fp8 e4m3 + EXACT fp32 row sum-of-squares ----
__global__ void __launch_bounds__(256) k_convert_x(const float* __restrict__ x,
                                                   u8* __restrict__ xb,
                                                   float* __restrict__ xsq) {
  const int row = blockIdx.x * 4 + (threadIdx.x >> 6);
  const int l = threadIdx.x & 63;
  const float* xr = x + (size_t)row * INF;
  u32* xbr = reinterpret_cast<u32*>(xb + (size_t)row * INF);
  float s = 0.f;
  #pragma unroll
  for (int i = 0; i < 4; ++i) {
    const float4 v = reinterpret_cast<const float4*>(xr)[l + i * 64];
    xbr[l + i * 64] = pk4_fp8(v.x, v.y, v.z, v.w);
    s += v.x * v.x + v.y * v.y + v.z * v.z + v.w * v.w;
  }
  #pragma unroll
  for (int off = 32; off > 0; off >>= 1) s += __shfl_xor(s, off, 64);
  if (l == 0) xsq[row] = s;
}

// ---- w: fp32 [INF][OUTF] -> fp8 w^T [OUTF][INF] + per-column sq-partials ----
__global__ void __launch_bounds__(256) k_convert_w(const float* __restrict__ w,
                                                   u8* __restrict__ wt,
                                                   float* __restrict__ part) {
  __shared__ float tile[64][65];
  __shared__ float psum[4][64];
  const int n0 = blockIdx.x * 64;   // along OUTF
  const int k0 = blockIdx.y * 64;   // along INF
  const int tid = threadIdx.x;
  const int c = tid & 63, r4 = tid >> 6;
  float s = 0.f;
  #pragma unroll
  for (int i = 0; i < 16; ++i) {
    int k = r4 + i * 4;
    float v = w[(size_t)(k0 + k) * OUTF + n0 + c];   // coalesced over n
    tile[k][c] = v;
    s += v * v;
  }
  psum[r4][c] = s;
  __syncthreads();
  #pragma unroll
  for (int i = 0; i < 4; ++i) {
    const int n = (tid >> 4) + i * 16;      // 0..63
    const int kq = (tid & 15) * 4;          // 0..60
    u32 p = pk4_fp8(tile[kq][n], tile[kq + 1][n], tile[kq + 2][n], tile[kq + 3][n]);
    *reinterpret_cast<u32*>(wt + (size_t)(n0 + n) * INF + k0 + kq) = p;
  }
  if (r4 == 0)
    part[(size_t)blockIdx.y * OUTF + n0 + c] =
        psum[0][c] + psum[1][c] + psum[2][c] + psum[3][c];
}

// ---- fused GEMM (MX-fp8, unit scales): out = xsq[row] + wsq[col] - 2*(x@w) ----
// R9/R11 skeleton: 128x128 tile, 4 waves (2x2 of 64x64), multi-block residency,
// single-buffered 32 KiB LDS (A 16K @0, B 16K @16384), one stage+2 barriers per
// K-tile. BK=128 (NT=8), fp8 rows = 128 B; swizzle byte(r,c) = r*128 +
// (c ^ ((r&7)<<4)), both-sides (pre-swizzled gload source, swizzled ds_read).
// MFMA: mfma_scale_f32_32x32x64_f8f6f4, fmt fp8/fp8, E8M0 scale 0x7F = 1.0.
// Wave tile 64x64 = 2x2 of 32x32; A-frag: row=lane&31, k=(lane>>5)*32+[0..31].
// C/D 32x32: col=lane&31, row=(reg&3)+8*(reg>>2)+4*(lane>>5)  [m74/m101].
__global__ void __launch_bounds__(256, 4) k_gemm(const u8* __restrict__ A,
                                                 const u8* __restrict__ Bt,
                                                 const float* __restrict__ xsq,
                                                 const float* __restrict__ prt,
                                                 float* __restrict__ out) {
  __shared__ __attribute__((aligned(16))) char lds[32768];

  const int tid = threadIdx.x;
  const int wave = tid >> 6, lane = tid & 63;
  const int bid = blockIdx.x;
  const int xcd = bid & 7;
  const int idx = bid >> 3;                // 0..255
  const int bxn = xcd * 2 + (idx & 1);     // 0..15  (N block, XCD-pinned pair)
  const int by  = idx >> 1;                // 0..127 (M block)
  const int rowBase = by * BM;
  const int colBase = bxn * BN;
  const int wr = (wave >> 1) & 1, wc = wave & 1;   // 2x2 waves of 64x64

  // staging: thread covers row srow(+32i), 16 fp8 bytes at pre-swizzled col
  const int srow = tid >> 3;                                      // 0..31
  const int ke   = ((tid & 7) * 16) ^ (((tid >> 3) & 7) << 4);    // byte col
  const u8* aS = A  + (size_t)(rowBase + srow) * INF + ke;
  const u8* bS = Bt + (size_t)(colBase + srow) * INF + ke;
  char* ldsw = lds + tid * 16;

  // fragment read addressing
  const int r31 = lane & 31;
  const int kh  = lane >> 5;                 // k-half (0/1)
  const int swzr = (r31 & 7) << 4;           // row&7 (m*32, wr*64 are mult of 8)
  const int aBase = (wr * 64 + r31) * 128;          // + m*4096
  const int bBase = 16384 + (wc * 64 + r31) * 128;  // + n*4096

  f32x16 acc[2][2] = {};
  const int SC = 0x7f7f7f7f;                 // E8M0 = 127 -> scale 1.0 (any byte)

  for (int t = 0; t < NT; ++t) {
    __builtin_amdgcn_s_barrier();            // everyone done reading prev tile
    const int kk = t * BK;
    #pragma unroll
    for (int i = 0; i < 4; ++i)              // A rows [i*32, i*32+32)
      load_lds16(aS + (size_t)(i * 32) * INF + kk, ldsw + i * 4096);
    #pragma unroll
    for (int i = 0; i < 4; ++i)              // B rows
      load_lds16(bS + (size_t)(i * 32) * INF + kk, ldsw + 16384 + i * 4096);
    asm volatile("s_waitcnt vmcnt(0)" ::: "memory");
    __builtin_amdgcn_s_barrier();            // tile t staged for all waves

    #pragma unroll
    for (int kc = 0; kc < 2; ++kc) {
      const int cb0 = (kc * 64 + kh * 32) ^ swzr;
      const int cb1 = (kc * 64 + kh * 32 + 16) ^ swzr;
      i32x8 a[2], b[2];
      #pragma unroll
      for (int m = 0; m < 2; ++m) {
        i32x4 lo = *reinterpret_cast<const i32x4*>(lds + aBase + m * 4096 + cb0);
        i32x4 hi = *reinterpret_cast<const i32x4*>(lds + aBase + m * 4096 + cb1);
        a[m] = __builtin_shufflevector(lo, hi, 0, 1, 2, 3, 4, 5, 6, 7);
      }
      #pragma unroll
      for (int n = 0; n < 2; ++n) {
        i32x4 lo = *reinterpret_cast<const i32x4*>(lds + bBase + n * 4096 + cb0);
        i32x4 hi = *reinterpret_cast<const i32x4*>(lds + bBase + n * 4096 + cb1);
        b[n] = __builtin_shufflevector(lo, hi, 0, 1, 2, 3, 4, 5, 6, 7);
      }
      __builtin_amdgcn_s_setprio(1);
      #pragma unroll
      for (int m = 0; m < 2; ++m)
        #pragma unroll
        for (int n = 0; n < 2; ++n)
          acc[m][n] = __builtin_amdgcn_mfma_scale_f32_32x32x64_f8f6f4(
              a[m], b[n], acc[m][n], 0, 0, 0, SC, 0, SC);
      __builtin_amdgcn_s_setprio(0);
    }
  }

  // ---- epilogue: wsq from partials via dead LDS, then fused write ----
  __syncthreads();                            // all waves done with A/B in LDS
  float* wlds = reinterpret_cast<float*>(lds);
  if (tid < BN) {
    float sw = 0.f;
    #pragma unroll
    for (int kb = 0; kb < 16; ++kb)
      sw += prt[(size_t)kb * OUTF + colBase + tid];
    wlds[tid] = sw;
  }
  __syncthreads();

  #pragma unroll
  for (int m = 0; m < 2; ++m) {
    #pragma unroll
    for (int reg = 0; reg < 16; ++reg) {
      const int rowf = (reg & 3) + 8 * (reg >> 2) + 4 * kh;
      const int row = rowBase + wr * 64 + m * 32 + rowf;
      const float xs = xsq[row];
      #pragma unroll
      for (int n = 0; n < 2; ++n) {
        const int col = colBase + wc * 64 + n * 32 + r31;
        out[(size_t)row * OUTF + col] = xs + wlds[wc * 64 + n * 32 + r31]
                                        - 2.0f * acc[m][n][reg];
      }
    }
  }
}

extern "C" void kernel_launch(void* const* d_in, const int* in_sizes, int n_in,
                              void* d_out, int out_size, void* d_ws, size_t ws_size,
                              hipStream_t stream) {
  const float* x = (const float*)d_in[0];
  const float* w = (const float*)d_in[1];
  float* out = (float*)d_out;

  char* ws = (char*)d_ws;
  u8* xb     = (u8*)(ws);                     // 16384*1024   = 16777216 B
  u8* wt     = (u8*)(ws + 16777216);          // 2048*1024    =  2097152 B (B^T fp8)
  float* xsq = (float*)(ws + 18874368);       // 16384*4      =    65536 B
  float* prt = (float*)(ws + 18939904);       // 16*2048*4    =   131072 B

  k_convert_x<<<BATCH / 4, 256, 0, stream>>>(x, xb, xsq);
  k_convert_w<<<dim3(OUTF / 64, INF / 64), 256, 0, stream>>>(w, wt, prt);
  k_gemm<<<(BATCH / BM) * (OUTF / BN), 256, 0, stream>>>(xb, wt, xsq, prt, out);
}